// Round 10
// baseline (1202.018 us; speedup 1.0000x reference)
//
#include <hip/hip_runtime.h>
#include <hip/hip_bf16.h>

constexpr int cB = 32, cN = 64, cL = 64, cT = 10, cD = 256, cH = 512, cH3 = 1536;
constexpr int cBN = cB * cN;   // 2048
constexpr int cNP1 = cN + 1;   // 65: hidden tape, slot 0 = h0, slot n+1 = hs[:,n,:]

// ---------------- x[bn][d] = sum_l emb[sents[bn][l]][d] ----------------
__global__ void k_embed_x(const int* __restrict__ sents, const float* __restrict__ emb,
                          float* __restrict__ x) {
  __shared__ int idx[cL];
  int bn = blockIdx.x, t = threadIdx.x;
  if (t < cL) idx[t] = sents[bn * cL + t];
  __syncthreads();
  float acc = 0.f;
#pragma unroll 8
  for (int l = 0; l < cL; ++l) acc += emb[(long)idx[l] * cD + t];
  x[bn * cD + t] = acc;
}

// ---------------- tsum[b][d] = sum_t emb[titles[b][0][t]][d] ----------------
__global__ void k_title(const int* __restrict__ titles, const float* __restrict__ emb,
                        float* __restrict__ tsum) {
  __shared__ int idx[cT];
  int b = blockIdx.x, t = threadIdx.x;
  if (t < cT) idx[t] = titles[b * cN * cT + t];
  __syncthreads();
  float acc = 0.f;
#pragma unroll
  for (int i = 0; i < cT; ++i) acc += emb[(long)idx[i] * cD + t];
  tsum[b * cD + t] = acc;
}

// ---------------- h0 = tsum @ Wt + bt -> hse slot 0 ----------------
__global__ void k_h0(const float* __restrict__ tsum, const float* __restrict__ Wt,
                     const float* __restrict__ bt, float* __restrict__ hse) {
  int i = blockIdx.x * blockDim.x + threadIdx.x;  // B*H
  int b = i >> 9, hh = i & (cH - 1);
  const float* ts = tsum + b * cD;
  float acc = bt[hh];
  for (int k = 0; k < cD; ++k) acc += ts[k] * Wt[(long)k * cH + hh];
  hse[(long)b * cNP1 * cH + hh] = acc;
}

// ---------------- GI = X @ W_ih + b_ih ----------------
// grid (3 col-groups, 256 row-groups); block 256; C=2 cols/thread, M=8 rows
__global__ void k_gi(const float* __restrict__ x, const float* __restrict__ W_ih,
                     const float* __restrict__ b_ih, float* __restrict__ gi) {
  __shared__ float4 s4[8 * 64];                    // 8 rows x 256 k (8 KB)
  int cg = blockIdx.x;
  int row0 = blockIdx.y * 8;
  int t = threadIdx.x;
  const float4* x4 = (const float4*)(x + (long)row0 * cD);
  for (int i = t; i < 8 * 64; i += 256) s4[i] = x4[i];  // rows contiguous
  __syncthreads();
  int col0 = cg * 512 + t * 2;
  float2 acc[8];
#pragma unroll
  for (int m = 0; m < 8; ++m) acc[m] = make_float2(0.f, 0.f);
#pragma unroll 2
  for (int k4 = 0; k4 < 64; ++k4) {
    const float* wrow = W_ih + (long)(k4 * 4) * cH3 + col0;
    float2 w0 = *(const float2*)(wrow);
    float2 w1 = *(const float2*)(wrow + cH3);
    float2 w2 = *(const float2*)(wrow + 2 * cH3);
    float2 w3 = *(const float2*)(wrow + 3 * cH3);
#pragma unroll
    for (int m = 0; m < 8; ++m) {
      float4 a = s4[m * 64 + k4];
      acc[m].x += a.x * w0.x + a.y * w1.x + a.z * w2.x + a.w * w3.x;
      acc[m].y += a.x * w0.y + a.y * w1.y + a.z * w2.y + a.w * w3.y;
    }
  }
  float2 bb = *(const float2*)(b_ih + col0);
#pragma unroll
  for (int m = 0; m < 8; ++m)
    *(float2*)(gi + (long)(row0 + m) * cH3 + col0) =
        make_float2(acc[m].x + bb.x, acc[m].y + bb.y);
}

// ---------------- one GRU step (v3: LDS-free, barrier-free) ----------------
// grid 512 = bg(16: 2 batches) x cg(32: 16 cols/gate); block 256
// t = b*128 + c4*32 + kp : kp in [0,32) 16-k slice, c4 in [0,4) 4 cols, b in [0,2)
__device__ __forceinline__ float gru_gate(float R, float Z, float Nn, float ir,
                                          float iz, float inn, float h) {
  float r = 1.f / (1.f + __expf(-(ir + R)));
  float z = 1.f / (1.f + __expf(-(iz + Z)));
  float n = tanhf(inn + r * Nn);
  return (1.f - z) * n + z * h;
}
__global__ void k_gru_step(const float* __restrict__ gi, const float* __restrict__ W_hh,
                           const float* __restrict__ b_hh, float* __restrict__ hse, int step) {
  int cg = blockIdx.x & 31;
  int bg = blockIdx.x >> 5;
  int t = threadIdx.x;
  int kp = t & 31, c4 = (t >> 5) & 3, b = t >> 7;
  int col0 = cg * 16 + c4 * 4;
  const float* hrow = hse + ((long)(bg * 2 + b) * cNP1 + step) * cH;
  int k0 = kp * 16;
  float4 h0 = *(const float4*)(hrow + k0);
  float4 h1 = *(const float4*)(hrow + k0 + 4);
  float4 h2 = *(const float4*)(hrow + k0 + 8);
  float4 h3 = *(const float4*)(hrow + k0 + 12);
  float4 ar = make_float4(0, 0, 0, 0), az = ar, an = ar;
#define GRU_K(HV, KOFF)                                                     \
  {                                                                         \
    const float* wp = W_hh + (long)(k0 + (KOFF)) * cH3 + col0;              \
    float4 wr = *(const float4*)(wp);                                       \
    float4 wz = *(const float4*)(wp + cH);                                  \
    float4 wn = *(const float4*)(wp + 2 * cH);                              \
    ar.x += (HV)*wr.x; ar.y += (HV)*wr.y; ar.z += (HV)*wr.z; ar.w += (HV)*wr.w; \
    az.x += (HV)*wz.x; az.y += (HV)*wz.y; az.z += (HV)*wz.z; az.w += (HV)*wz.w; \
    an.x += (HV)*wn.x; an.y += (HV)*wn.y; an.z += (HV)*wn.z; an.w += (HV)*wn.w; \
  }
  GRU_K(h0.x, 0) GRU_K(h0.y, 1) GRU_K(h0.z, 2) GRU_K(h0.w, 3)
  GRU_K(h1.x, 4) GRU_K(h1.y, 5) GRU_K(h1.z, 6) GRU_K(h1.w, 7)
  GRU_K(h2.x, 8) GRU_K(h2.y, 9) GRU_K(h2.z, 10) GRU_K(h2.w, 11)
  GRU_K(h3.x, 12) GRU_K(h3.y, 13) GRU_K(h3.z, 14) GRU_K(h3.w, 15)
#undef GRU_K
  // reduce over kp within each 32-lane half (xor bits 0..4 stay in-half)
#pragma unroll
  for (int off = 16; off >= 1; off >>= 1) {
    ar.x += __shfl_xor(ar.x, off); ar.y += __shfl_xor(ar.y, off);
    ar.z += __shfl_xor(ar.z, off); ar.w += __shfl_xor(ar.w, off);
    az.x += __shfl_xor(az.x, off); az.y += __shfl_xor(az.y, off);
    az.z += __shfl_xor(az.z, off); az.w += __shfl_xor(az.w, off);
    an.x += __shfl_xor(an.x, off); an.y += __shfl_xor(an.y, off);
    an.z += __shfl_xor(an.z, off); an.w += __shfl_xor(an.w, off);
  }
  if (kp == 0) {
    int bb = bg * 2 + b;
    int hh = col0;
    long girow = ((long)bb * cN + step) * cH3;
    float4 bhr = *(const float4*)(b_hh + hh);
    float4 bhz = *(const float4*)(b_hh + cH + hh);
    float4 bhn = *(const float4*)(b_hh + 2 * cH + hh);
    float4 gr = *(const float4*)(gi + girow + hh);
    float4 gz = *(const float4*)(gi + girow + cH + hh);
    float4 gn = *(const float4*)(gi + girow + 2 * cH + hh);
    float4 ho = *(const float4*)(hrow + hh);
    float4 o;
    o.x = gru_gate(ar.x + bhr.x, az.x + bhz.x, an.x + bhn.x, gr.x, gz.x, gn.x, ho.x);
    o.y = gru_gate(ar.y + bhr.y, az.y + bhz.y, an.y + bhn.y, gr.y, gz.y, gn.y, ho.y);
    o.z = gru_gate(ar.z + bhr.z, az.z + bhz.z, an.z + bhn.z, gr.z, gz.z, gn.z, ho.z);
    o.w = gru_gate(ar.w + bhr.w, az.w + bhz.w, an.w + bhn.w, gr.w, gz.w, gn.w, ho.w);
    *(float4*)(hse + ((long)bb * cNP1 + step + 1) * cH + hh) = o;
  }
}

// ---------------- q partials: qp[kp][bn][col], k-split 2 ----------------
// grid (2 kp, 256 row-groups); block 256; C=2, M=8
__global__ void k_qp(const float* __restrict__ hse, const float* __restrict__ W,
                     float* __restrict__ qp) {
  __shared__ float4 s4[8 * 64];                    // 8 rows x 256-k slice (8 KB)
  int kp = blockIdx.x;
  int row0 = blockIdx.y * 8;
  int t = threadIdx.x;
  for (int i = t; i < 8 * 64; i += 256) {
    int m = i >> 6, k4 = i & 63;
    int bn = row0 + m;
    int b = bn >> 6, n = bn & 63;
    s4[i] = ((const float4*)(hse + ((long)b * cNP1 + 1 + n) * cH))[kp * 64 + k4];
  }
  __syncthreads();
  int col0 = t * 2;
  float2 acc[8];
#pragma unroll
  for (int m = 0; m < 8; ++m) acc[m] = make_float2(0.f, 0.f);
#pragma unroll 2
  for (int k4 = 0; k4 < 64; ++k4) {
    const float* wrow = W + (long)(kp * 256 + k4 * 4) * cH + col0;
    float2 w0 = *(const float2*)(wrow);
    float2 w1 = *(const float2*)(wrow + cH);
    float2 w2 = *(const float2*)(wrow + 2 * cH);
    float2 w3 = *(const float2*)(wrow + 3 * cH);
#pragma unroll
    for (int m = 0; m < 8; ++m) {
      float4 a = s4[m * 64 + k4];
      acc[m].x += a.x * w0.x + a.y * w1.x + a.z * w2.x + a.w * w3.x;
      acc[m].y += a.x * w0.y + a.y * w1.y + a.z * w2.y + a.w * w3.y;
    }
  }
#pragma unroll
  for (int m = 0; m < 8; ++m)
    *(float2*)(qp + ((long)kp * cBN + row0 + m) * cH + col0) = acc[m];
}

// ---------------- causal attention (q = qp0+qp1 folded into staging) ----------------
__global__ void k_attn(const float* __restrict__ qp, const float* __restrict__ hse,
                       float* __restrict__ c) {
  __shared__ float qs[cH];
  __shared__ float part[256];
  __shared__ float aw[cN];
  int bn = blockIdx.x;
  int b = bn >> 6, n = bn & 63;
  int t = threadIdx.x;
  const float* q0 = qp + (long)bn * cH;
  const float* q1 = qp + ((long)cBN + bn) * cH;
  qs[t] = q0[t] + q1[t];
  qs[t + 256] = q0[t + 256] + q1[t + 256];
  __syncthreads();
  int k = t & 63;
  int p = t >> 6;  // 4 partials per key
  const float* hrow = hse + ((long)b * cNP1 + 1 + k) * cH + p * 128;
  float s = 0.f;
#pragma unroll 8
  for (int j = 0; j < 128; ++j) s += qs[p * 128 + j] * hrow[j];
  part[t] = s;
  __syncthreads();
  if (t < 64) {
    float sc = part[t] + part[t + 64] + part[t + 128] + part[t + 192];
    if (t > n) sc = -1e30f;  // ref adds log(1e-45) ~ -103.6 -> exp underflows to 0
    float m = sc;
#pragma unroll
    for (int off = 32; off; off >>= 1) m = fmaxf(m, __shfl_xor(m, off));
    float e = __expf(sc - m);
    float sum = e;
#pragma unroll
    for (int off = 32; off; off >>= 1) sum += __shfl_xor(sum, off);
    aw[t] = e / sum;
  }
  __syncthreads();
  float c0 = 0.f, c1 = 0.f;
  for (int kk = 0; kk < cN; ++kk) {
    float a = aw[kk];
    const float* hr = hse + ((long)b * cNP1 + 1 + kk) * cH;
    c0 += a * hr[t];
    c1 += a * hr[t + 256];
  }
  c[(long)bn * cH + t] = c0;
  c[(long)bn * cH + t + 256] = c1;
}

// ---------------- out partials over concat halves ----------------
// grid (256 row-groups, 2 kp); block 256; C=2, M=8
__global__ void k_outp(const float* __restrict__ c, const float* __restrict__ hse,
                       const float* __restrict__ W, float* __restrict__ pko) {
  __shared__ float4 s4[8 * 128];                   // 16 KB
  int row0 = blockIdx.x * 8;
  int kp = blockIdx.y;
  int t = threadIdx.x;
  for (int i = t; i < 8 * 128; i += 256) {
    int m = i >> 7, k4 = i & 127;
    int bn = row0 + m;
    int b = bn >> 6, n = bn & 63;
    const float4* src = (kp == 0) ? (const float4*)(c + (long)bn * cH)
                                  : (const float4*)(hse + ((long)b * cNP1 + 1 + n) * cH);
    s4[i] = src[k4];
  }
  __syncthreads();
  int col0 = t * 2;
  float2 acc[8];
#pragma unroll
  for (int m = 0; m < 8; ++m) acc[m] = make_float2(0.f, 0.f);
#pragma unroll 2
  for (int k4 = 0; k4 < 128; ++k4) {
    const float* wrow = W + (long)(kp * cH + k4 * 4) * cH + col0;
    float2 w0 = *(const float2*)(wrow);
    float2 w1 = *(const float2*)(wrow + cH);
    float2 w2 = *(const float2*)(wrow + 2 * cH);
    float2 w3 = *(const float2*)(wrow + 3 * cH);
#pragma unroll
    for (int m = 0; m < 8; ++m) {
      float4 a = s4[m * 128 + k4];
      acc[m].x += a.x * w0.x + a.y * w1.x + a.z * w2.x + a.w * w3.x;
      acc[m].y += a.x * w0.y + a.y * w1.y + a.z * w2.y + a.w * w3.y;
    }
  }
#pragma unroll
  for (int m = 0; m < 8; ++m)
    *(float2*)(pko + ((long)kp * cBN + row0 + m) * cH + col0) = acc[m];
}

// ---------------- out = tanh(p0 + p1 + bias) ----------------
__global__ void k_outr(const float* __restrict__ pko, const float* __restrict__ bias,
                       float* __restrict__ out) {
  int bn = blockIdx.x, col = threadIdx.x;  // 512 threads
  long i = (long)bn * cH + col;
  out[i] = tanhf(pko[i] + pko[(long)cBN * cH + i] + bias[col]);
}

extern "C" void kernel_launch(void* const* d_in, const int* in_sizes, int n_in,
                              void* d_out, int out_size, void* d_ws, size_t ws_size,
                              hipStream_t stream) {
  const int* sents = (const int*)d_in[0];
  const int* titles = (const int*)d_in[1];
  const float* emb = (const float*)d_in[2];
  const float* Wt = (const float*)d_in[3];
  const float* bt = (const float*)d_in[4];
  const float* W_ih = (const float*)d_in[5];
  const float* W_hh = (const float*)d_in[6];
  const float* b_ih = (const float*)d_in[7];
  const float* b_hh = (const float*)d_in[8];
  const float* W_att_in = (const float*)d_in[9];
  const float* W_att_out = (const float*)d_in[10];
  const float* b_att_out = (const float*)d_in[11];
  float* out = (float*)d_out;

  float* ws = (float*)d_ws;
  float* x = ws;                                   // BN*D
  float* tsum = x + (long)cBN * cD;                // B*D
  float* gi = tsum + (long)cB * cD;                // BN*3H (dead after scan)
  float* hse = gi + (long)cBN * cH3;               // B*65*H
  float* c = hse + (long)cB * cNP1 * cH;           // BN*H
  float* qp = gi;                                  // 2*BN*H q-partials alias dead gi
  float* pko = gi;                                 // out-partials reuse same region after k_attn

  k_embed_x<<<cBN, 256, 0, stream>>>(sents, emb, x);
  k_title<<<cB, 256, 0, stream>>>(titles, emb, tsum);
  k_h0<<<(cB * cH) / 256, 256, 0, stream>>>(tsum, Wt, bt, hse);
  k_gi<<<dim3(3, cBN / 8), 256, 0, stream>>>(x, W_ih, b_ih, gi);
  for (int step = 0; step < cN; ++step)
    k_gru_step<<<512, 256, 0, stream>>>(gi, W_hh, b_hh, hse, step);
  k_qp<<<dim3(2, cBN / 8), 256, 0, stream>>>(hse, W_att_in, qp);
  k_attn<<<cBN, 256, 0, stream>>>(qp, hse, c);
  k_outp<<<dim3(cBN / 8, 2), 256, 0, stream>>>(c, hse, W_att_out, pko);
  k_outr<<<cBN, 512, 0, stream>>>(pko, b_att_out, out);
}

// Round 11
// 629.158 us; speedup vs baseline: 1.9105x; 1.9105x over previous
//
#include <hip/hip_runtime.h>
#include <hip/hip_bf16.h>

constexpr int cB = 32, cN = 64, cL = 64, cT = 10, cD = 256, cH = 512, cH3 = 1536;
constexpr int cBN = cB * cN;   // 2048
constexpr int cNP1 = cN + 1;   // 65: hidden tape, slot 0 = h0, slot n+1 = hs[:,n,:]

// ---------------- x[bn][d] = sum_l emb[sents[bn][l]][d] ----------------
__global__ void k_embed_x(const int* __restrict__ sents, const float* __restrict__ emb,
                          float* __restrict__ x) {
  __shared__ int idx[cL];
  int bn = blockIdx.x, t = threadIdx.x;
  if (t < cL) idx[t] = sents[bn * cL + t];
  __syncthreads();
  float acc = 0.f;
#pragma unroll 8
  for (int l = 0; l < cL; ++l) acc += emb[(long)idx[l] * cD + t];
  x[bn * cD + t] = acc;
}

// ---------------- tsum[b][d] = sum_t emb[titles[b][0][t]][d] ----------------
__global__ void k_title(const int* __restrict__ titles, const float* __restrict__ emb,
                        float* __restrict__ tsum) {
  __shared__ int idx[cT];
  int b = blockIdx.x, t = threadIdx.x;
  if (t < cT) idx[t] = titles[b * cN * cT + t];
  __syncthreads();
  float acc = 0.f;
#pragma unroll
  for (int i = 0; i < cT; ++i) acc += emb[(long)idx[i] * cD + t];
  tsum[b * cD + t] = acc;
}

// ---------------- h0 = tsum @ Wt + bt -> hse slot 0 ----------------
__global__ void k_h0(const float* __restrict__ tsum, const float* __restrict__ Wt,
                     const float* __restrict__ bt, float* __restrict__ hse) {
  int i = blockIdx.x * blockDim.x + threadIdx.x;  // B*H
  int b = i >> 9, hh = i & (cH - 1);
  const float* ts = tsum + b * cD;
  float acc = bt[hh];
  for (int k = 0; k < cD; ++k) acc += ts[k] * Wt[(long)k * cH + hh];
  hse[(long)b * cNP1 * cH + hh] = acc;
}

// ---------------- GI = X @ W_ih + b_ih ----------------
// grid (3 cg, 512 rowg); block 128; C=4 cols/thread, M=4 rows/block
__global__ void k_gi(const float* __restrict__ x, const float* __restrict__ W_ih,
                     const float* __restrict__ b_ih, float* __restrict__ gi) {
  __shared__ float4 s4[4 * 64];                    // 4 rows x 256 k (4 KB)
  int cg = blockIdx.x;
  int row0 = blockIdx.y * 4;
  int t = threadIdx.x;
  const float4* x4 = (const float4*)(x + (long)row0 * cD);
  for (int i = t; i < 4 * 64; i += 128) s4[i] = x4[i];  // rows contiguous
  __syncthreads();
  int col0 = cg * 512 + t * 4;
  float4 acc[4];
#pragma unroll
  for (int m = 0; m < 4; ++m) acc[m] = make_float4(0.f, 0.f, 0.f, 0.f);
#pragma unroll 4
  for (int k4 = 0; k4 < 64; ++k4) {
    const float* wrow = W_ih + (long)(k4 * 4) * cH3 + col0;
    float4 w0 = *(const float4*)(wrow);
    float4 w1 = *(const float4*)(wrow + cH3);
    float4 w2 = *(const float4*)(wrow + 2 * cH3);
    float4 w3 = *(const float4*)(wrow + 3 * cH3);
#pragma unroll
    for (int m = 0; m < 4; ++m) {
      float4 a = s4[m * 64 + k4];
      acc[m].x += a.x * w0.x + a.y * w1.x + a.z * w2.x + a.w * w3.x;
      acc[m].y += a.x * w0.y + a.y * w1.y + a.z * w2.y + a.w * w3.y;
      acc[m].z += a.x * w0.z + a.y * w1.z + a.z * w2.z + a.w * w3.z;
      acc[m].w += a.x * w0.w + a.y * w1.w + a.z * w2.w + a.w * w3.w;
    }
  }
  float4 bb = *(const float4*)(b_ih + col0);
#pragma unroll
  for (int m = 0; m < 4; ++m)
    *(float4*)(gi + (long)(row0 + m) * cH3 + col0) =
        make_float4(acc[m].x + bb.x, acc[m].y + bb.y, acc[m].z + bb.z, acc[m].w + bb.w);
}

// ---------------- one GRU step (r7-proven; epilogue widened to 64 lanes) ----------------
// grid 512 = bg(16: 2 batches) x cg(32: 16 cols/gate); block 256
__global__ void k_gru_step(const float* __restrict__ gi, const float* __restrict__ W_hh,
                           const float* __restrict__ b_hh, float* __restrict__ hse, int step) {
  __shared__ float hsm[2][cH];
  __shared__ float part[256][13];   // stride 13: conflict-free partial writes
  int cg = blockIdx.x & 31;
  int bg = blockIdx.x >> 5;
  int t = threadIdx.x;
  {  // stage 2 hidden rows (4 KB)
    int m = t >> 7, k4 = t & 127;
    const float4* r4 = (const float4*)(hse + ((long)(bg * 2 + m) * cNP1 + step) * cH);
    ((float4*)&hsm[m][0])[k4] = r4[k4];
  }
  __syncthreads();
  int c4 = t & 3, b = (t >> 2) & 1, kp = t >> 3;
  int col0 = cg * 16 + c4 * 4;
  float ar[4] = {0, 0, 0, 0}, az[4] = {0, 0, 0, 0}, an[4] = {0, 0, 0, 0};
  int k0 = kp * 16;
#pragma unroll
  for (int k = k0; k < k0 + 16; ++k) {
    float hv = hsm[b][k];
    const float* wp = W_hh + (long)k * cH3 + col0;
    float4 wr = *(const float4*)(wp);
    float4 wz = *(const float4*)(wp + cH);
    float4 wn = *(const float4*)(wp + 2 * cH);
    ar[0] += hv * wr.x; ar[1] += hv * wr.y; ar[2] += hv * wr.z; ar[3] += hv * wr.w;
    az[0] += hv * wz.x; az[1] += hv * wz.y; az[2] += hv * wz.z; az[3] += hv * wz.w;
    an[0] += hv * wn.x; an[1] += hv * wn.y; an[2] += hv * wn.z; an[3] += hv * wn.w;
  }
#pragma unroll
  for (int j = 0; j < 4; ++j) {
    part[t][j] = ar[j];
    part[t][4 + j] = az[j];
    part[t][8 + j] = an[j];
  }
  __syncthreads();
  if (t < 64) {  // one wave64: 32 outputs x 2 half-sums, combined by shfl across lane^32
    int o = t & 31, h2 = t >> 5;
    int b_l = o >> 4, cl = o & 15;
    int c4f = cl >> 2, jf = cl & 3;
    float sr = 0.f, sz = 0.f, sn = 0.f;
#pragma unroll
    for (int p = h2 * 16; p < h2 * 16 + 16; ++p) {
      const float* pp = part[p * 8 + b_l * 4 + c4f];
      sr += pp[jf];
      sz += pp[4 + jf];
      sn += pp[8 + jf];
    }
    sr += __shfl_xor(sr, 32);
    sz += __shfl_xor(sz, 32);
    sn += __shfl_xor(sn, 32);
    if (h2 == 0) {
      int bb = bg * 2 + b_l;
      int hh = cg * 16 + cl;
      long girow = ((long)bb * cN + step) * cH3;
      float R = sr + b_hh[hh];
      float Z = sz + b_hh[hh + cH];
      float Nn = sn + b_hh[hh + 2 * cH];
      float ir = gi[girow + hh];
      float iz = gi[girow + hh + cH];
      float in_ = gi[girow + hh + 2 * cH];
      float rr = 1.f / (1.f + __expf(-(ir + R)));
      float zz = 1.f / (1.f + __expf(-(iz + Z)));
      float nn = tanhf(in_ + rr * Nn);
      hse[((long)bb * cNP1 + step + 1) * cH + hh] = (1.f - zz) * nn + zz * hsm[b_l][hh];
    }
  }
}

// ---------------- q partials: qp[kp][bn][col], k-split 2 ----------------
// grid (2 kp, 512 rowg); block 256; C=2, M=4
__global__ void k_qp(const float* __restrict__ hse, const float* __restrict__ W,
                     float* __restrict__ qp) {
  __shared__ float4 s4[4 * 64];                    // 4 rows x 256-k slice (4 KB)
  int kp = blockIdx.x;
  int row0 = blockIdx.y * 4;
  int t = threadIdx.x;
  {
    int i = t;  // 256 entries, 1 per thread
    int m = i >> 6, k4 = i & 63;
    int bn = row0 + m;
    int b = bn >> 6, n = bn & 63;
    s4[i] = ((const float4*)(hse + ((long)b * cNP1 + 1 + n) * cH))[kp * 64 + k4];
  }
  __syncthreads();
  int col0 = t * 2;
  float2 acc[4];
#pragma unroll
  for (int m = 0; m < 4; ++m) acc[m] = make_float2(0.f, 0.f);
#pragma unroll 4
  for (int k4 = 0; k4 < 64; ++k4) {
    const float* wrow = W + (long)(kp * 256 + k4 * 4) * cH + col0;
    float2 w0 = *(const float2*)(wrow);
    float2 w1 = *(const float2*)(wrow + cH);
    float2 w2 = *(const float2*)(wrow + 2 * cH);
    float2 w3 = *(const float2*)(wrow + 3 * cH);
#pragma unroll
    for (int m = 0; m < 4; ++m) {
      float4 a = s4[m * 64 + k4];
      acc[m].x += a.x * w0.x + a.y * w1.x + a.z * w2.x + a.w * w3.x;
      acc[m].y += a.x * w0.y + a.y * w1.y + a.z * w2.y + a.w * w3.y;
    }
  }
#pragma unroll
  for (int m = 0; m < 4; ++m)
    *(float2*)(qp + ((long)kp * cBN + row0 + m) * cH + col0) = acc[m];
}

// ---------------- causal attention (q = qp0+qp1 folded into staging) ----------------
__global__ void k_attn(const float* __restrict__ qp, const float* __restrict__ hse,
                       float* __restrict__ c) {
  __shared__ float qs[cH];
  __shared__ float part[256];
  __shared__ float aw[cN];
  int bn = blockIdx.x;
  int b = bn >> 6, n = bn & 63;
  int t = threadIdx.x;
  const float* q0 = qp + (long)bn * cH;
  const float* q1 = qp + ((long)cBN + bn) * cH;
  qs[t] = q0[t] + q1[t];
  qs[t + 256] = q0[t + 256] + q1[t + 256];
  __syncthreads();
  int k = t & 63;
  int p = t >> 6;  // 4 partials per key
  const float* hrow = hse + ((long)b * cNP1 + 1 + k) * cH + p * 128;
  float s = 0.f;
#pragma unroll 8
  for (int j = 0; j < 128; ++j) s += qs[p * 128 + j] * hrow[j];
  part[t] = s;
  __syncthreads();
  if (t < 64) {
    float sc = part[t] + part[t + 64] + part[t + 128] + part[t + 192];
    if (t > n) sc = -1e30f;  // ref adds log(1e-45) ~ -103.6 -> exp underflows to 0
    float m = sc;
#pragma unroll
    for (int off = 32; off; off >>= 1) m = fmaxf(m, __shfl_xor(m, off));
    float e = __expf(sc - m);
    float sum = e;
#pragma unroll
    for (int off = 32; off; off >>= 1) sum += __shfl_xor(sum, off);
    aw[t] = e / sum;
  }
  __syncthreads();
  float c0 = 0.f, c1 = 0.f;
  for (int kk = 0; kk < cN; ++kk) {
    float a = aw[kk];
    const float* hr = hse + ((long)b * cNP1 + 1 + kk) * cH;
    c0 += a * hr[t];
    c1 += a * hr[t + 256];
  }
  c[(long)bn * cH + t] = c0;
  c[(long)bn * cH + t + 256] = c1;
}

// ---------------- out partials over concat halves ----------------
// grid (512 rowg, 2 kp); block 256; C=2, M=4
__global__ void k_outp(const float* __restrict__ c, const float* __restrict__ hse,
                       const float* __restrict__ W, float* __restrict__ pko) {
  __shared__ float4 s4[4 * 128];                   // 4 rows x 512-k half (8 KB)
  int row0 = blockIdx.x * 4;
  int kp = blockIdx.y;
  int t = threadIdx.x;
  for (int i = t; i < 4 * 128; i += 256) {
    int m = i >> 7, k4 = i & 127;
    int bn = row0 + m;
    int b = bn >> 6, n = bn & 63;
    const float4* src = (kp == 0) ? (const float4*)(c + (long)bn * cH)
                                  : (const float4*)(hse + ((long)b * cNP1 + 1 + n) * cH);
    s4[i] = src[k4];
  }
  __syncthreads();
  int col0 = t * 2;
  float2 acc[4];
#pragma unroll
  for (int m = 0; m < 4; ++m) acc[m] = make_float2(0.f, 0.f);
#pragma unroll 4
  for (int k4 = 0; k4 < 128; ++k4) {
    const float* wrow = W + (long)(kp * cH + k4 * 4) * cH + col0;
    float2 w0 = *(const float2*)(wrow);
    float2 w1 = *(const float2*)(wrow + cH);
    float2 w2 = *(const float2*)(wrow + 2 * cH);
    float2 w3 = *(const float2*)(wrow + 3 * cH);
#pragma unroll
    for (int m = 0; m < 4; ++m) {
      float4 a = s4[m * 128 + k4];
      acc[m].x += a.x * w0.x + a.y * w1.x + a.z * w2.x + a.w * w3.x;
      acc[m].y += a.x * w0.y + a.y * w1.y + a.z * w2.y + a.w * w3.y;
    }
  }
#pragma unroll
  for (int m = 0; m < 4; ++m)
    *(float2*)(pko + ((long)kp * cBN + row0 + m) * cH + col0) = acc[m];
}

// ---------------- out = tanh(p0 + p1 + bias) ----------------
__global__ void k_outr(const float* __restrict__ pko, const float* __restrict__ bias,
                       float* __restrict__ out) {
  int bn = blockIdx.x, col = threadIdx.x;  // 512 threads
  long i = (long)bn * cH + col;
  out[i] = tanhf(pko[i] + pko[(long)cBN * cH + i] + bias[col]);
}

extern "C" void kernel_launch(void* const* d_in, const int* in_sizes, int n_in,
                              void* d_out, int out_size, void* d_ws, size_t ws_size,
                              hipStream_t stream) {
  const int* sents = (const int*)d_in[0];
  const int* titles = (const int*)d_in[1];
  const float* emb = (const float*)d_in[2];
  const float* Wt = (const float*)d_in[3];
  const float* bt = (const float*)d_in[4];
  const float* W_ih = (const float*)d_in[5];
  const float* W_hh = (const float*)d_in[6];
  const float* b_ih = (const float*)d_in[7];
  const float* b_hh = (const float*)d_in[8];
  const float* W_att_in = (const float*)d_in[9];
  const float* W_att_out = (const float*)d_in[10];
  const float* b_att_out = (const float*)d_in[11];
  float* out = (float*)d_out;

  float* ws = (float*)d_ws;
  float* x = ws;                                   // BN*D
  float* tsum = x + (long)cBN * cD;                // B*D
  float* gi = tsum + (long)cB * cD;                // BN*3H (dead after scan)
  float* hse = gi + (long)cBN * cH3;               // B*65*H
  float* c = hse + (long)cB * cNP1 * cH;           // BN*H
  float* qp = gi;                                  // 2*BN*H q-partials alias dead gi
  float* pko = gi;                                 // out-partials reuse same region after k_attn

  k_embed_x<<<cBN, 256, 0, stream>>>(sents, emb, x);
  k_title<<<cB, 256, 0, stream>>>(titles, emb, tsum);
  k_h0<<<(cB * cH) / 256, 256, 0, stream>>>(tsum, Wt, bt, hse);
  k_gi<<<dim3(3, cBN / 4), 128, 0, stream>>>(x, W_ih, b_ih, gi);
  for (int step = 0; step < cN; ++step)
    k_gru_step<<<512, 256, 0, stream>>>(gi, W_hh, b_hh, hse, step);
  k_qp<<<dim3(2, cBN / 4), 256, 0, stream>>>(hse, W_att_in, qp);
  k_attn<<<cBN, 256, 0, stream>>>(qp, hse, c);
  k_outp<<<dim3(cBN / 4, 2), 256, 0, stream>>>(c, hse, W_att_out, pko);
  k_outr<<<cBN, 512, 0, stream>>>(pko, b_att_out, out);
}

// Round 12
// 596.057 us; speedup vs baseline: 2.0166x; 1.0555x over previous
//
#include <hip/hip_runtime.h>
#include <hip/hip_bf16.h>

constexpr int cB = 32, cN = 64, cL = 64, cT = 10, cD = 256, cH = 512, cH3 = 1536;
constexpr int cBN = cB * cN;   // 2048
constexpr int cNP1 = cN + 1;   // 65: hidden tape, slot 0 = h0, slot n+1 = hs[:,n,:]

// ---------------- x[bn][d] = sum_l emb[sents[bn][l]][d] ----------------
__global__ void k_embed_x(const int* __restrict__ sents, const float* __restrict__ emb,
                          float* __restrict__ x) {
  __shared__ int idx[cL];
  int bn = blockIdx.x, t = threadIdx.x;
  if (t < cL) idx[t] = sents[bn * cL + t];
  __syncthreads();
  float acc = 0.f;
#pragma unroll 8
  for (int l = 0; l < cL; ++l) acc += emb[(long)idx[l] * cD + t];
  x[bn * cD + t] = acc;
}

// ---------------- tsum[b][d] = sum_t emb[titles[b][0][t]][d] ----------------
__global__ void k_title(const int* __restrict__ titles, const float* __restrict__ emb,
                        float* __restrict__ tsum) {
  __shared__ int idx[cT];
  int b = blockIdx.x, t = threadIdx.x;
  if (t < cT) idx[t] = titles[b * cN * cT + t];
  __syncthreads();
  float acc = 0.f;
#pragma unroll
  for (int i = 0; i < cT; ++i) acc += emb[(long)idx[i] * cD + t];
  tsum[b * cD + t] = acc;
}

// ---------------- h0 = tsum @ Wt + bt -> hse slot 0 ----------------
__global__ void k_h0(const float* __restrict__ tsum, const float* __restrict__ Wt,
                     const float* __restrict__ bt, float* __restrict__ hse) {
  int i = blockIdx.x * blockDim.x + threadIdx.x;  // B*H
  int b = i >> 9, hh = i & (cH - 1);
  const float* ts = tsum + b * cD;
  float acc = bt[hh];
  for (int k = 0; k < cD; ++k) acc += ts[k] * Wt[(long)k * cH + hh];
  hse[(long)b * cNP1 * cH + hh] = acc;
}

// ---------------- GI = X @ W_ih + b_ih ----------------
// grid (3 cg, 512 rowg); block 128; C=4 cols/thread, M=4 rows/block
__global__ void __launch_bounds__(128, 3) k_gi(
    const float* __restrict__ x, const float* __restrict__ W_ih,
    const float* __restrict__ b_ih, float* __restrict__ gi) {
  __shared__ float4 s4[4 * 64];                    // 4 rows x 256 k (4 KB)
  int cg = blockIdx.x;
  int row0 = blockIdx.y * 4;
  int t = threadIdx.x;
  const float4* x4 = (const float4*)(x + (long)row0 * cD);
  for (int i = t; i < 4 * 64; i += 128) s4[i] = x4[i];  // rows contiguous
  __syncthreads();
  int col0 = cg * 512 + t * 4;
  float4 acc[4];
#pragma unroll
  for (int m = 0; m < 4; ++m) acc[m] = make_float4(0.f, 0.f, 0.f, 0.f);
#pragma unroll 8
  for (int k4 = 0; k4 < 64; ++k4) {
    const float* wrow = W_ih + (long)(k4 * 4) * cH3 + col0;
    float4 w0 = *(const float4*)(wrow);
    float4 w1 = *(const float4*)(wrow + cH3);
    float4 w2 = *(const float4*)(wrow + 2 * cH3);
    float4 w3 = *(const float4*)(wrow + 3 * cH3);
#pragma unroll
    for (int m = 0; m < 4; ++m) {
      float4 a = s4[m * 64 + k4];
      acc[m].x += a.x * w0.x + a.y * w1.x + a.z * w2.x + a.w * w3.x;
      acc[m].y += a.x * w0.y + a.y * w1.y + a.z * w2.y + a.w * w3.y;
      acc[m].z += a.x * w0.z + a.y * w1.z + a.z * w2.z + a.w * w3.z;
      acc[m].w += a.x * w0.w + a.y * w1.w + a.z * w2.w + a.w * w3.w;
    }
  }
  float4 bb = *(const float4*)(b_ih + col0);
#pragma unroll
  for (int m = 0; m < 4; ++m)
    *(float4*)(gi + (long)(row0 + m) * cH3 + col0) =
        make_float4(acc[m].x + bb.x, acc[m].y + bb.y, acc[m].z + bb.z, acc[m].w + bb.w);
}

// ---------------- one GRU step (r10-proven; +VGPR headroom, +gi prefetch) ----------------
// grid 512 = bg(16: 2 batches) x cg(32: 16 cols/gate); block 256
__global__ void __launch_bounds__(256, 4) k_gru_step(
    const float* __restrict__ gi, const float* __restrict__ W_hh,
    const float* __restrict__ b_hh, float* __restrict__ hse, int step) {
  __shared__ float hsm[2][cH];
  __shared__ float part[256][13];   // stride 13: conflict-free partial writes
  int cg = blockIdx.x & 31;
  int bg = blockIdx.x >> 5;
  int t = threadIdx.x;

  // epilogue operands prefetched at entry (independent of matmul; hides L2/HBM latency)
  float ir = 0.f, iz = 0.f, in_ = 0.f, bhr = 0.f, bhz = 0.f, bhn = 0.f;
  int eo = t & 31, eh2 = t >> 5;  // epilogue lane mapping (used when t < 64)
  int e_bl = eo >> 4, e_cl = eo & 15;
  if (t < 64) {
    int bb = bg * 2 + e_bl;
    int hh = cg * 16 + e_cl;
    long girow = ((long)bb * cN + step) * cH3;
    ir = gi[girow + hh];
    iz = gi[girow + hh + cH];
    in_ = gi[girow + hh + 2 * cH];
    bhr = b_hh[hh];
    bhz = b_hh[hh + cH];
    bhn = b_hh[hh + 2 * cH];
  }

  {  // stage 2 hidden rows (4 KB)
    int m = t >> 7, k4 = t & 127;
    const float4* r4 = (const float4*)(hse + ((long)(bg * 2 + m) * cNP1 + step) * cH);
    ((float4*)&hsm[m][0])[k4] = r4[k4];
  }
  __syncthreads();
  int c4 = t & 3, b = (t >> 2) & 1, kp = t >> 3;
  int col0 = cg * 16 + c4 * 4;
  float ar[4] = {0, 0, 0, 0}, az[4] = {0, 0, 0, 0}, an[4] = {0, 0, 0, 0};
  int k0 = kp * 16;
#pragma unroll
  for (int k = k0; k < k0 + 16; ++k) {
    float hv = hsm[b][k];
    const float* wp = W_hh + (long)k * cH3 + col0;
    float4 wr = *(const float4*)(wp);
    float4 wz = *(const float4*)(wp + cH);
    float4 wn = *(const float4*)(wp + 2 * cH);
    ar[0] += hv * wr.x; ar[1] += hv * wr.y; ar[2] += hv * wr.z; ar[3] += hv * wr.w;
    az[0] += hv * wz.x; az[1] += hv * wz.y; az[2] += hv * wz.z; az[3] += hv * wz.w;
    an[0] += hv * wn.x; an[1] += hv * wn.y; an[2] += hv * wn.z; an[3] += hv * wn.w;
  }
#pragma unroll
  for (int j = 0; j < 4; ++j) {
    part[t][j] = ar[j];
    part[t][4 + j] = az[j];
    part[t][8 + j] = an[j];
  }
  __syncthreads();
  if (t < 64) {  // one wave64: 32 outputs x 2 half-sums, combined by shfl across lane^32
    int c4f = e_cl >> 2, jf = e_cl & 3;
    float sr = 0.f, sz = 0.f, sn = 0.f;
#pragma unroll
    for (int p = eh2 * 16; p < eh2 * 16 + 16; ++p) {
      const float* pp = part[p * 8 + e_bl * 4 + c4f];
      sr += pp[jf];
      sz += pp[4 + jf];
      sn += pp[8 + jf];
    }
    sr += __shfl_xor(sr, 32);
    sz += __shfl_xor(sz, 32);
    sn += __shfl_xor(sn, 32);
    if (eh2 == 0) {
      int bb = bg * 2 + e_bl;
      int hh = cg * 16 + e_cl;
      float R = sr + bhr;
      float Z = sz + bhz;
      float Nn = sn + bhn;
      float rr = 1.f / (1.f + __expf(-(ir + R)));
      float zz = 1.f / (1.f + __expf(-(iz + Z)));
      float nn = tanhf(in_ + rr * Nn);
      hse[((long)bb * cNP1 + step + 1) * cH + hh] = (1.f - zz) * nn + zz * hsm[e_bl][hh];
    }
  }
}

// ---------------- q partials: qp[kp][bn][col], k-split 2 ----------------
// grid (2 kp, 512 rowg); block 256; C=2, M=4
__global__ void __launch_bounds__(256, 4) k_qp(
    const float* __restrict__ hse, const float* __restrict__ W, float* __restrict__ qp) {
  __shared__ float4 s4[4 * 64];                    // 4 rows x 256-k slice (4 KB)
  int kp = blockIdx.x;
  int row0 = blockIdx.y * 4;
  int t = threadIdx.x;
  {
    int i = t;  // 256 entries, 1 per thread
    int m = i >> 6, k4 = i & 63;
    int bn = row0 + m;
    int b = bn >> 6, n = bn & 63;
    s4[i] = ((const float4*)(hse + ((long)b * cNP1 + 1 + n) * cH))[kp * 64 + k4];
  }
  __syncthreads();
  int col0 = t * 2;
  float2 acc[4];
#pragma unroll
  for (int m = 0; m < 4; ++m) acc[m] = make_float2(0.f, 0.f);
#pragma unroll 8
  for (int k4 = 0; k4 < 64; ++k4) {
    const float* wrow = W + (long)(kp * 256 + k4 * 4) * cH + col0;
    float2 w0 = *(const float2*)(wrow);
    float2 w1 = *(const float2*)(wrow + cH);
    float2 w2 = *(const float2*)(wrow + 2 * cH);
    float2 w3 = *(const float2*)(wrow + 3 * cH);
#pragma unroll
    for (int m = 0; m < 4; ++m) {
      float4 a = s4[m * 64 + k4];
      acc[m].x += a.x * w0.x + a.y * w1.x + a.z * w2.x + a.w * w3.x;
      acc[m].y += a.x * w0.y + a.y * w1.y + a.z * w2.y + a.w * w3.y;
    }
  }
#pragma unroll
  for (int m = 0; m < 4; ++m)
    *(float2*)(qp + ((long)kp * cBN + row0 + m) * cH + col0) = acc[m];
}

// ---------------- causal attention (q = qp0+qp1 folded into staging) ----------------
__global__ void k_attn(const float* __restrict__ qp, const float* __restrict__ hse,
                       float* __restrict__ c) {
  __shared__ float qs[cH];
  __shared__ float part[256];
  __shared__ float aw[cN];
  int bn = blockIdx.x;
  int b = bn >> 6, n = bn & 63;
  int t = threadIdx.x;
  const float* q0 = qp + (long)bn * cH;
  const float* q1 = qp + ((long)cBN + bn) * cH;
  qs[t] = q0[t] + q1[t];
  qs[t + 256] = q0[t + 256] + q1[t + 256];
  __syncthreads();
  int k = t & 63;
  int p = t >> 6;  // 4 partials per key
  const float* hrow = hse + ((long)b * cNP1 + 1 + k) * cH + p * 128;
  float s = 0.f;
#pragma unroll 8
  for (int j = 0; j < 128; ++j) s += qs[p * 128 + j] * hrow[j];
  part[t] = s;
  __syncthreads();
  if (t < 64) {
    float sc = part[t] + part[t + 64] + part[t + 128] + part[t + 192];
    if (t > n) sc = -1e30f;  // ref adds log(1e-45) ~ -103.6 -> exp underflows to 0
    float m = sc;
#pragma unroll
    for (int off = 32; off; off >>= 1) m = fmaxf(m, __shfl_xor(m, off));
    float e = __expf(sc - m);
    float sum = e;
#pragma unroll
    for (int off = 32; off; off >>= 1) sum += __shfl_xor(sum, off);
    aw[t] = e / sum;
  }
  __syncthreads();
  float c0 = 0.f, c1 = 0.f;
  for (int kk = 0; kk < cN; ++kk) {
    float a = aw[kk];
    const float* hr = hse + ((long)b * cNP1 + 1 + kk) * cH;
    c0 += a * hr[t];
    c1 += a * hr[t + 256];
  }
  c[(long)bn * cH + t] = c0;
  c[(long)bn * cH + t + 256] = c1;
}

// ---------------- out partials over concat halves ----------------
// grid (512 rowg, 2 kp); block 256; C=2, M=4
__global__ void __launch_bounds__(256, 4) k_outp(
    const float* __restrict__ c, const float* __restrict__ hse,
    const float* __restrict__ W, float* __restrict__ pko) {
  __shared__ float4 s4[4 * 128];                   // 4 rows x 512-k half (8 KB)
  int row0 = blockIdx.x * 4;
  int kp = blockIdx.y;
  int t = threadIdx.x;
  for (int i = t; i < 4 * 128; i += 256) {
    int m = i >> 7, k4 = i & 127;
    int bn = row0 + m;
    int b = bn >> 6, n = bn & 63;
    const float4* src = (kp == 0) ? (const float4*)(c + (long)bn * cH)
                                  : (const float4*)(hse + ((long)b * cNP1 + 1 + n) * cH);
    s4[i] = src[k4];
  }
  __syncthreads();
  int col0 = t * 2;
  float2 acc[4];
#pragma unroll
  for (int m = 0; m < 4; ++m) acc[m] = make_float2(0.f, 0.f);
#pragma unroll 8
  for (int k4 = 0; k4 < 128; ++k4) {
    const float* wrow = W + (long)(kp * cH + k4 * 4) * cH + col0;
    float2 w0 = *(const float2*)(wrow);
    float2 w1 = *(const float2*)(wrow + cH);
    float2 w2 = *(const float2*)(wrow + 2 * cH);
    float2 w3 = *(const float2*)(wrow + 3 * cH);
#pragma unroll
    for (int m = 0; m < 4; ++m) {
      float4 a = s4[m * 128 + k4];
      acc[m].x += a.x * w0.x + a.y * w1.x + a.z * w2.x + a.w * w3.x;
      acc[m].y += a.x * w0.y + a.y * w1.y + a.z * w2.y + a.w * w3.y;
    }
  }
#pragma unroll
  for (int m = 0; m < 4; ++m)
    *(float2*)(pko + ((long)kp * cBN + row0 + m) * cH + col0) = acc[m];
}

// ---------------- out = tanh(p0 + p1 + bias) ----------------
__global__ void k_outr(const float* __restrict__ pko, const float* __restrict__ bias,
                       float* __restrict__ out) {
  int bn = blockIdx.x, col = threadIdx.x;  // 512 threads
  long i = (long)bn * cH + col;
  out[i] = tanhf(pko[i] + pko[(long)cBN * cH + i] + bias[col]);
}

extern "C" void kernel_launch(void* const* d_in, const int* in_sizes, int n_in,
                              void* d_out, int out_size, void* d_ws, size_t ws_size,
                              hipStream_t stream) {
  const int* sents = (const int*)d_in[0];
  const int* titles = (const int*)d_in[1];
  const float* emb = (const float*)d_in[2];
  const float* Wt = (const float*)d_in[3];
  const float* bt = (const float*)d_in[4];
  const float* W_ih = (const float*)d_in[5];
  const float* W_hh = (const float*)d_in[6];
  const float* b_ih = (const float*)d_in[7];
  const float* b_hh = (const float*)d_in[8];
  const float* W_att_in = (const float*)d_in[9];
  const float* W_att_out = (const float*)d_in[10];
  const float* b_att_out = (const float*)d_in[11];
  float* out = (float*)d_out;

  float* ws = (float*)d_ws;
  float* x = ws;                                   // BN*D
  float* tsum = x + (long)cBN * cD;                // B*D
  float* gi = tsum + (long)cB * cD;                // BN*3H (dead after scan)
  float* hse = gi + (long)cBN * cH3;               // B*65*H
  float* c = hse + (long)cB * cNP1 * cH;           // BN*H
  float* qp = gi;                                  // 2*BN*H q-partials alias dead gi
  float* pko = gi;                                 // out-partials reuse same region after k_attn

  k_embed_x<<<cBN, 256, 0, stream>>>(sents, emb, x);
  k_title<<<cB, 256, 0, stream>>>(titles, emb, tsum);
  k_h0<<<(cB * cH) / 256, 256, 0, stream>>>(tsum, Wt, bt, hse);
  k_gi<<<dim3(3, cBN / 4), 128, 0, stream>>>(x, W_ih, b_ih, gi);
  for (int step = 0; step < cN; ++step)
    k_gru_step<<<512, 256, 0, stream>>>(gi, W_hh, b_hh, hse, step);
  k_qp<<<dim3(2, cBN / 4), 256, 0, stream>>>(hse, W_att_in, qp);
  k_attn<<<cBN, 256, 0, stream>>>(qp, hse, c);
  k_outp<<<dim3(cBN / 4, 2), 256, 0, stream>>>(c, hse, W_att_out, pko);
  k_outr<<<cBN, 512, 0, stream>>>(pko, b_att_out, out);
}

// Round 13
// 556.137 us; speedup vs baseline: 2.1614x; 1.0718x over previous
//
#include <hip/hip_runtime.h>
#include <hip/hip_bf16.h>

constexpr int cB = 32, cN = 64, cL = 64, cT = 10, cD = 256, cH = 512, cH3 = 1536;
constexpr int cBN = cB * cN;   // 2048
constexpr int cNP1 = cN + 1;   // 65: hidden tape, slot 0 = h0, slot n+1 = hs[:,n,:]

// ---------------- x[bn][d] = sum_l emb[sents[bn][l]][d] ----------------
__global__ void k_embed_x(const int* __restrict__ sents, const float* __restrict__ emb,
                          float* __restrict__ x) {
  __shared__ int idx[cL];
  int bn = blockIdx.x, t = threadIdx.x;
  if (t < cL) idx[t] = sents[bn * cL + t];
  __syncthreads();
  float acc = 0.f;
#pragma unroll 8
  for (int l = 0; l < cL; ++l) acc += emb[(long)idx[l] * cD + t];
  x[bn * cD + t] = acc;
}

// ---------------- tsum[b][d] = sum_t emb[titles[b][0][t]][d] ----------------
__global__ void k_title(const int* __restrict__ titles, const float* __restrict__ emb,
                        float* __restrict__ tsum) {
  __shared__ int idx[cT];
  int b = blockIdx.x, t = threadIdx.x;
  if (t < cT) idx[t] = titles[b * cN * cT + t];
  __syncthreads();
  float acc = 0.f;
#pragma unroll
  for (int i = 0; i < cT; ++i) acc += emb[(long)idx[i] * cD + t];
  tsum[b * cD + t] = acc;
}

// ---------------- h0 = tsum @ Wt + bt -> hse slot 0 ----------------
__global__ void k_h0(const float* __restrict__ tsum, const float* __restrict__ Wt,
                     const float* __restrict__ bt, float* __restrict__ hse) {
  int i = blockIdx.x * blockDim.x + threadIdx.x;  // B*H
  int b = i >> 9, hh = i & (cH - 1);
  const float* ts = tsum + b * cD;
  float acc = bt[hh];
  for (int k = 0; k < cD; ++k) acc += ts[k] * Wt[(long)k * cH + hh];
  hse[(long)b * cNP1 * cH + hh] = acc;
}

// ---------------- GI = X @ W_ih + b_ih ----------------
// grid (3 cg, 512 rowg); block 128; C=4 cols/thread, M=4 rows/block
__global__ void __launch_bounds__(128, 3) k_gi(
    const float* __restrict__ x, const float* __restrict__ W_ih,
    const float* __restrict__ b_ih, float* __restrict__ gi) {
  __shared__ float4 s4[4 * 64];                    // 4 rows x 256 k (4 KB)
  int cg = blockIdx.x;
  int row0 = blockIdx.y * 4;
  int t = threadIdx.x;
  const float4* x4 = (const float4*)(x + (long)row0 * cD);
  for (int i = t; i < 4 * 64; i += 128) s4[i] = x4[i];  // rows contiguous
  __syncthreads();
  int col0 = cg * 512 + t * 4;
  float4 acc[4];
#pragma unroll
  for (int m = 0; m < 4; ++m) acc[m] = make_float4(0.f, 0.f, 0.f, 0.f);
#pragma unroll 8
  for (int k4 = 0; k4 < 64; ++k4) {
    const float* wrow = W_ih + (long)(k4 * 4) * cH3 + col0;
    float4 w0 = *(const float4*)(wrow);
    float4 w1 = *(const float4*)(wrow + cH3);
    float4 w2 = *(const float4*)(wrow + 2 * cH3);
    float4 w3 = *(const float4*)(wrow + 3 * cH3);
#pragma unroll
    for (int m = 0; m < 4; ++m) {
      float4 a = s4[m * 64 + k4];
      acc[m].x += a.x * w0.x + a.y * w1.x + a.z * w2.x + a.w * w3.x;
      acc[m].y += a.x * w0.y + a.y * w1.y + a.z * w2.y + a.w * w3.y;
      acc[m].z += a.x * w0.z + a.y * w1.z + a.z * w2.z + a.w * w3.z;
      acc[m].w += a.x * w0.w + a.y * w1.w + a.z * w2.w + a.w * w3.w;
    }
  }
  float4 bb = *(const float4*)(b_ih + col0);
#pragma unroll
  for (int m = 0; m < 4; ++m)
    *(float4*)(gi + (long)(row0 + m) * cH3 + col0) =
        make_float4(acc[m].x + bb.x, acc[m].y + bb.y, acc[m].z + bb.z, acc[m].w + bb.w);
}

// ---------------- one GRU step (v4: 4 batches/block, 512 thr, W traffic halved) ----------------
// grid 256 = bg(8: 4 batches) x cg(32: 16 cols/gate); block 512
// t = kp(t>>4: 32 parts, 16 k each) | b((t>>2)&3) | c4(t&3)
__global__ void __launch_bounds__(512, 1) k_gru_step(
    const float* __restrict__ gi, const float* __restrict__ W_hh,
    const float* __restrict__ b_hh, float* __restrict__ hse, int step) {
  __shared__ float hsm[4][cH + 4];    // pad 4: float4-aligned rows (516*4=2064=129*16)
  __shared__ float part[512][13];     // stride 13: conflict-free partial writes
  int cg = blockIdx.x & 31;
  int bg = blockIdx.x >> 5;
  int t = threadIdx.x;

  // epilogue operands prefetched at entry (t < 64: one lane per output)
  float ir = 0.f, iz = 0.f, in_ = 0.f, bhr = 0.f, bhz = 0.f, bhn = 0.f;
  int e_bl = (t >> 4) & 3, e_cl = t & 15;
  if (t < 64) {
    int bb = bg * 4 + e_bl;
    int hh = cg * 16 + e_cl;
    long girow = ((long)bb * cN + step) * cH3;
    ir = gi[girow + hh];
    iz = gi[girow + hh + cH];
    in_ = gi[girow + hh + 2 * cH];
    bhr = b_hh[hh];
    bhz = b_hh[hh + cH];
    bhn = b_hh[hh + 2 * cH];
  }

  {  // stage 4 hidden rows (8 KB): 512 threads x 1 float4
    int m = t >> 7, k4 = t & 127;
    const float4* r4 = (const float4*)(hse + ((long)(bg * 4 + m) * cNP1 + step) * cH);
    ((float4*)&hsm[m][0])[k4] = r4[k4];
  }
  __syncthreads();
  int c4 = t & 3, b = (t >> 2) & 3, kp = t >> 4;
  int col0 = cg * 16 + c4 * 4;
  float ar[4] = {0, 0, 0, 0}, az[4] = {0, 0, 0, 0}, an[4] = {0, 0, 0, 0};
  int k0 = kp * 16;
#pragma unroll
  for (int k = k0; k < k0 + 16; ++k) {
    float hv = hsm[b][k];
    const float* wp = W_hh + (long)k * cH3 + col0;
    float4 wr = *(const float4*)(wp);
    float4 wz = *(const float4*)(wp + cH);
    float4 wn = *(const float4*)(wp + 2 * cH);
    ar[0] += hv * wr.x; ar[1] += hv * wr.y; ar[2] += hv * wr.z; ar[3] += hv * wr.w;
    az[0] += hv * wz.x; az[1] += hv * wz.y; az[2] += hv * wz.z; az[3] += hv * wz.w;
    an[0] += hv * wn.x; an[1] += hv * wn.y; an[2] += hv * wn.z; an[3] += hv * wn.w;
  }
#pragma unroll
  for (int j = 0; j < 4; ++j) {
    part[t][j] = ar[j];
    part[t][4 + j] = az[j];
    part[t][8 + j] = an[j];
  }
  __syncthreads();
  if (t < 64) {  // 64 outputs, each lane sums its 32 partials
    int c4f = e_cl >> 2, jf = e_cl & 3;
    float sr = 0.f, sz = 0.f, sn = 0.f;
#pragma unroll
    for (int p = 0; p < 32; ++p) {
      const float* pp = part[p * 16 + e_bl * 4 + c4f];
      sr += pp[jf];
      sz += pp[4 + jf];
      sn += pp[8 + jf];
    }
    int bb = bg * 4 + e_bl;
    int hh = cg * 16 + e_cl;
    float R = sr + bhr;
    float Z = sz + bhz;
    float Nn = sn + bhn;
    float rr = 1.f / (1.f + __expf(-(ir + R)));
    float zz = 1.f / (1.f + __expf(-(iz + Z)));
    float nn = tanhf(in_ + rr * Nn);
    hse[((long)bb * cNP1 + step + 1) * cH + hh] = (1.f - zz) * nn + zz * hsm[e_bl][hh];
  }
}

// ---------------- q partials: qp[kp][bn][col], k-split 2 ----------------
// grid (2 kp, 512 rowg); block 256; C=2, M=4
__global__ void __launch_bounds__(256, 4) k_qp(
    const float* __restrict__ hse, const float* __restrict__ W, float* __restrict__ qp) {
  __shared__ float4 s4[4 * 64];                    // 4 rows x 256-k slice (4 KB)
  int kp = blockIdx.x;
  int row0 = blockIdx.y * 4;
  int t = threadIdx.x;
  {
    int i = t;  // 256 entries, 1 per thread
    int m = i >> 6, k4 = i & 63;
    int bn = row0 + m;
    int b = bn >> 6, n = bn & 63;
    s4[i] = ((const float4*)(hse + ((long)b * cNP1 + 1 + n) * cH))[kp * 64 + k4];
  }
  __syncthreads();
  int col0 = t * 2;
  float2 acc[4];
#pragma unroll
  for (int m = 0; m < 4; ++m) acc[m] = make_float2(0.f, 0.f);
#pragma unroll 8
  for (int k4 = 0; k4 < 64; ++k4) {
    const float* wrow = W + (long)(kp * 256 + k4 * 4) * cH + col0;
    float2 w0 = *(const float2*)(wrow);
    float2 w1 = *(const float2*)(wrow + cH);
    float2 w2 = *(const float2*)(wrow + 2 * cH);
    float2 w3 = *(const float2*)(wrow + 3 * cH);
#pragma unroll
    for (int m = 0; m < 4; ++m) {
      float4 a = s4[m * 64 + k4];
      acc[m].x += a.x * w0.x + a.y * w1.x + a.z * w2.x + a.w * w3.x;
      acc[m].y += a.x * w0.y + a.y * w1.y + a.z * w2.y + a.w * w3.y;
    }
  }
#pragma unroll
  for (int m = 0; m < 4; ++m)
    *(float2*)(qp + ((long)kp * cBN + row0 + m) * cH + col0) = acc[m];
}

// ---------------- causal attention (q = qp0+qp1 folded into staging) ----------------
__global__ void k_attn(const float* __restrict__ qp, const float* __restrict__ hse,
                       float* __restrict__ c) {
  __shared__ float qs[cH];
  __shared__ float part[256];
  __shared__ float aw[cN];
  int bn = blockIdx.x;
  int b = bn >> 6, n = bn & 63;
  int t = threadIdx.x;
  const float* q0 = qp + (long)bn * cH;
  const float* q1 = qp + ((long)cBN + bn) * cH;
  qs[t] = q0[t] + q1[t];
  qs[t + 256] = q0[t + 256] + q1[t + 256];
  __syncthreads();
  int k = t & 63;
  int p = t >> 6;  // 4 partials per key
  const float* hrow = hse + ((long)b * cNP1 + 1 + k) * cH + p * 128;
  float s = 0.f;
#pragma unroll 8
  for (int j = 0; j < 128; ++j) s += qs[p * 128 + j] * hrow[j];
  part[t] = s;
  __syncthreads();
  if (t < 64) {
    float sc = part[t] + part[t + 64] + part[t + 128] + part[t + 192];
    if (t > n) sc = -1e30f;  // ref adds log(1e-45) ~ -103.6 -> exp underflows to 0
    float m = sc;
#pragma unroll
    for (int off = 32; off; off >>= 1) m = fmaxf(m, __shfl_xor(m, off));
    float e = __expf(sc - m);
    float sum = e;
#pragma unroll
    for (int off = 32; off; off >>= 1) sum += __shfl_xor(sum, off);
    aw[t] = e / sum;
  }
  __syncthreads();
  float c0 = 0.f, c1 = 0.f;
  for (int kk = 0; kk < cN; ++kk) {
    float a = aw[kk];
    const float* hr = hse + ((long)b * cNP1 + 1 + kk) * cH;
    c0 += a * hr[t];
    c1 += a * hr[t + 256];
  }
  c[(long)bn * cH + t] = c0;
  c[(long)bn * cH + t + 256] = c1;
}

// ---------------- out = tanh(concat(c,hs) @ W_att_out + b)  (direct, in-block k-reduce) ----------------
// grid (4 colg, 256 rowg); block 128; M=8, C=4, S=4 k-quarters reduced in LDS
__global__ void __launch_bounds__(128, 2) k_out(
    const float* __restrict__ c, const float* __restrict__ hse,
    const float* __restrict__ W, const float* __restrict__ bias, float* __restrict__ out) {
  __shared__ float4 s4[8 * 256];        // 32 KB: 8 rows x 1024 k (concat)
  __shared__ float part[96][33];        // 12.4 KB partials, stride-33 conflict-free
  int colg = blockIdx.x;
  int row0 = blockIdx.y * 8;
  int t = threadIdx.x;
  for (int i = t; i < 8 * 256; i += 128) {
    int m = i >> 8, k4 = i & 255;
    int bn = row0 + m;
    int b = bn >> 6, n = bn & 63;
    s4[i] = (k4 < 128) ? ((const float4*)(c + (long)bn * cH))[k4]
                       : ((const float4*)(hse + ((long)b * cNP1 + 1 + n) * cH))[k4 - 128];
  }
  __syncthreads();
  int s = t >> 5, tc = t & 31;
  int col0 = colg * 128 + tc * 4;
  float4 acc[8];
#pragma unroll
  for (int m = 0; m < 8; ++m) acc[m] = make_float4(0.f, 0.f, 0.f, 0.f);
  int k4lo = s * 64;
#pragma unroll 4
  for (int k4 = k4lo; k4 < k4lo + 64; ++k4) {
    float4 a[8];
#pragma unroll
    for (int m = 0; m < 8; ++m) a[m] = s4[m * 256 + k4];
#pragma unroll
    for (int j = 0; j < 4; ++j) {
      float4 w = *(const float4*)(W + (long)(k4 * 4 + j) * cH + col0);
#pragma unroll
      for (int m = 0; m < 8; ++m) {
        float av = (j == 0) ? a[m].x : (j == 1) ? a[m].y : (j == 2) ? a[m].z : a[m].w;
        acc[m].x += av * w.x; acc[m].y += av * w.y;
        acc[m].z += av * w.z; acc[m].w += av * w.w;
      }
    }
  }
  if (s > 0) {
    float* pr = part[(s - 1) * 32 + tc];
#pragma unroll
    for (int m = 0; m < 8; ++m) {
      pr[m * 4 + 0] = acc[m].x; pr[m * 4 + 1] = acc[m].y;
      pr[m * 4 + 2] = acc[m].z; pr[m * 4 + 3] = acc[m].w;
    }
  }
  __syncthreads();
  if (s == 0) {
    float4 b4 = *(const float4*)(bias + col0);
#pragma unroll
    for (int m = 0; m < 8; ++m) {
      float4 o = acc[m];
#pragma unroll
      for (int ss = 0; ss < 3; ++ss) {
        const float* pr = part[ss * 32 + tc];
        o.x += pr[m * 4 + 0]; o.y += pr[m * 4 + 1];
        o.z += pr[m * 4 + 2]; o.w += pr[m * 4 + 3];
      }
      float4 r = make_float4(tanhf(o.x + b4.x), tanhf(o.y + b4.y),
                             tanhf(o.z + b4.z), tanhf(o.w + b4.w));
      *(float4*)(out + (long)(row0 + m) * cH + col0) = r;
    }
  }
}

extern "C" void kernel_launch(void* const* d_in, const int* in_sizes, int n_in,
                              void* d_out, int out_size, void* d_ws, size_t ws_size,
                              hipStream_t stream) {
  const int* sents = (const int*)d_in[0];
  const int* titles = (const int*)d_in[1];
  const float* emb = (const float*)d_in[2];
  const float* Wt = (const float*)d_in[3];
  const float* bt = (const float*)d_in[4];
  const float* W_ih = (const float*)d_in[5];
  const float* W_hh = (const float*)d_in[6];
  const float* b_ih = (const float*)d_in[7];
  const float* b_hh = (const float*)d_in[8];
  const float* W_att_in = (const float*)d_in[9];
  const float* W_att_out = (const float*)d_in[10];
  const float* b_att_out = (const float*)d_in[11];
  float* out = (float*)d_out;

  float* ws = (float*)d_ws;
  float* x = ws;                                   // BN*D
  float* tsum = x + (long)cBN * cD;                // B*D
  float* gi = tsum + (long)cB * cD;                // BN*3H (dead after scan)
  float* hse = gi + (long)cBN * cH3;               // B*65*H
  float* c = hse + (long)cB * cNP1 * cH;           // BN*H
  float* qp = gi;                                  // 2*BN*H q-partials alias dead gi

  k_embed_x<<<cBN, 256, 0, stream>>>(sents, emb, x);
  k_title<<<cB, 256, 0, stream>>>(titles, emb, tsum);
  k_h0<<<(cB * cH) / 256, 256, 0, stream>>>(tsum, Wt, bt, hse);
  k_gi<<<dim3(3, cBN / 4), 128, 0, stream>>>(x, W_ih, b_ih, gi);
  for (int step = 0; step < cN; ++step)
    k_gru_step<<<256, 512, 0, stream>>>(gi, W_hh, b_hh, hse, step);
  k_qp<<<dim3(2, cBN / 4), 256, 0, stream>>>(hse, W_att_in, qp);
  k_attn<<<cBN, 256, 0, stream>>>(qp, hse, c);
  k_out<<<dim3(4, cBN / 8), 128, 0, stream>>>(c, hse, W_att_out, b_att_out, out);
}